// Round 9
// baseline (234.131 us; speedup 1.0000x reference)
//
#include <hip/hip_runtime.h>
#include <hip/hip_bf16.h>

// SelfAttention: B=8, C=512, W=2048, CR=64
// proj_qk -> proj_v -> stats(l only, no max) -> context v8.
// context v8: block=(b, j-tile 32), grid 512 = 2 blocks/CU (TLP fills
// barrier-round stalls). S partitioned by j (computed once globally).
// Counted-vmcnt raw barrier + deep prefetch (v7 discipline).

#define B 8
#define C 512
#define W 2048
#define CR 64
static constexpr float SCALE = 0.125f; // 64^-0.5

typedef __bf16 bf16x8 __attribute__((ext_vector_type(8)));
typedef float f32x4 __attribute__((ext_vector_type(4)));

__device__ inline ushort f2bs(float f) {
    __hip_bfloat16 h = __float2bfloat16(f);
    return *reinterpret_cast<ushort*>(&h);
}
__device__ inline f32x4 mfma16(bf16x8 a, bf16x8 b, f32x4 c) {
    return __builtin_amdgcn_mfma_f32_16x16x32_bf16(a, b, c, 0, 0, 0);
}

// ---------- proj q+k fused: per (w-tile 64, b). K=512 step 64. N=64 (d).
__global__ __launch_bounds__(256) void proj_qk_kernel(
    const float* __restrict__ x, const float* __restrict__ wqf, const float* __restrict__ wkf,
    const float* __restrict__ bq, const float* __restrict__ bk,
    ushort* __restrict__ qT, ushort* __restrict__ kT)
{
    __shared__ __align__(16) ushort xt[64][72];   // [w][c]
    __shared__ __align__(16) ushort wq_s[64][72]; // [d][c]
    __shared__ __align__(16) ushort wk_s[64][72];
    const int b = blockIdx.y, w0 = blockIdx.x * 64;
    const int t = threadIdx.x;
    const int wid = t >> 6, lane = t & 63;
    const int wm = wid >> 1, wn = wid & 1;
    const int lr = lane & 15, lg = lane >> 4;

    f32x4 aq[2][2] = {};
    f32x4 ak[2][2] = {};

    for (int k0 = 0; k0 < C; k0 += 64) {
        __syncthreads();
        for (int idx = t; idx < 64 * 64; idx += 256) {
            int c = idx >> 6, w = idx & 63;
            xt[w][c] = f2bs(x[(b * C + k0 + c) * W + w0 + w]);
        }
        for (int idx = t; idx < 64 * 64; idx += 256) {
            int d = idx >> 6, c = idx & 63;
            wq_s[d][c] = f2bs(wqf[d * C + k0 + c]);
            wk_s[d][c] = f2bs(wkf[d * C + k0 + c]);
        }
        __syncthreads();
        #pragma unroll
        for (int kk = 0; kk < 2; ++kk) {
            int ko = kk * 32 + (lg << 3);
            bf16x8 a[2], fq[2], fk[2];
            #pragma unroll
            for (int mf = 0; mf < 2; ++mf)
                a[mf] = *(const bf16x8*)&xt[wm * 32 + mf * 16 + lr][ko];
            #pragma unroll
            for (int nf = 0; nf < 2; ++nf) {
                fq[nf] = *(const bf16x8*)&wq_s[wn * 32 + nf * 16 + lr][ko];
                fk[nf] = *(const bf16x8*)&wk_s[wn * 32 + nf * 16 + lr][ko];
            }
            #pragma unroll
            for (int mf = 0; mf < 2; ++mf)
                #pragma unroll
                for (int nf = 0; nf < 2; ++nf) {
                    aq[mf][nf] = mfma16(a[mf], fq[nf], aq[mf][nf]);
                    ak[mf][nf] = mfma16(a[mf], fk[nf], ak[mf][nf]);
                }
        }
    }
    #pragma unroll
    for (int mf = 0; mf < 2; ++mf)
        #pragma unroll
        for (int nf = 0; nf < 2; ++nf)
            #pragma unroll
            for (int r = 0; r < 4; ++r) {
                int w = w0 + wm * 32 + mf * 16 + (lg << 2) + r;
                int d = wn * 32 + nf * 16 + lr;
                qT[(b * W + w) * CR + d] = f2bs(aq[mf][nf][r] + bq[d]);
                kT[(b * W + w) * CR + d] = f2bs(ak[mf][nf][r] + bk[d]);
            }
}

// ---------- proj v: per (w-tile 128, c-tile 128, b). K=512 step 64.
__global__ __launch_bounds__(256) void proj_v_kernel(
    const float* __restrict__ x, const float* __restrict__ wvf, const float* __restrict__ bv,
    ushort* __restrict__ v)
{
    __shared__ __align__(16) ushort wv_s[128][72]; // [c][cin]
    __shared__ __align__(16) ushort xt[128][72];   // [w][cin]
    const int b = blockIdx.z, c0 = blockIdx.y * 128, w0 = blockIdx.x * 128;
    const int t = threadIdx.x;
    const int wid = t >> 6, lane = t & 63;
    const int wm = wid >> 1, wn = wid & 1;
    const int lr = lane & 15, lg = lane >> 4;

    f32x4 acc[4][4] = {};
    for (int k0 = 0; k0 < C; k0 += 64) {
        __syncthreads();
        for (int idx = t; idx < 128 * 64; idx += 256) {
            int r = idx >> 6, c = idx & 63;
            wv_s[r][c] = f2bs(wvf[(c0 + r) * C + k0 + c]);
        }
        for (int idx = t; idx < 64 * 128; idx += 256) {
            int c = idx >> 7, w = idx & 127;
            xt[w][c] = f2bs(x[(b * C + k0 + c) * W + w0 + w]);
        }
        __syncthreads();
        #pragma unroll
        for (int kk = 0; kk < 2; ++kk) {
            int ko = kk * 32 + (lg << 3);
            bf16x8 a[4], bb[4];
            #pragma unroll
            for (int mf = 0; mf < 4; ++mf)
                a[mf] = *(const bf16x8*)&wv_s[wm * 64 + mf * 16 + lr][ko];
            #pragma unroll
            for (int nf = 0; nf < 4; ++nf)
                bb[nf] = *(const bf16x8*)&xt[wn * 64 + nf * 16 + lr][ko];
            #pragma unroll
            for (int mf = 0; mf < 4; ++mf)
                #pragma unroll
                for (int nf = 0; nf < 4; ++nf)
                    acc[mf][nf] = mfma16(a[mf], bb[nf], acc[mf][nf]);
        }
    }
    #pragma unroll
    for (int mf = 0; mf < 4; ++mf)
        #pragma unroll
        for (int nf = 0; nf < 4; ++nf)
            #pragma unroll
            for (int r = 0; r < 4; ++r) {
                int c = c0 + wm * 64 + mf * 16 + (lg << 2) + r;
                int w = w0 + wn * 64 + nf * 16 + lr;
                v[(b * C + c) * W + w] = f2bs(acc[mf][nf][r] + bv[c]);
            }
}

// ---------- stats v2: per (b, i-tile 64): l_i = sum_j exp(s_ij) (no max).
__global__ __launch_bounds__(512) void stats_kernel(
    const ushort* __restrict__ qT, const ushort* __restrict__ kT,
    float* __restrict__ ilrow)
{
    __shared__ float red[8][64];
    const int bid = blockIdx.x;
    const int b = bid & 7;            // XCD-affine
    const int i0 = (bid >> 3) * 64;
    const int t = threadIdx.x;
    const int w = t >> 6, lane = t & 63;
    const int lr = lane & 15, lg = lane >> 4;

    bf16x8 bq[4][2];
    #pragma unroll
    for (int nf = 0; nf < 4; ++nf)
        #pragma unroll
        for (int kk = 0; kk < 2; ++kk)
            bq[nf][kk] = *(const bf16x8*)&qT[(b * W + i0 + nf * 16 + lr) * CR + kk * 32 + (lg << 3)];

    float lacc[4] = {0.f, 0.f, 0.f, 0.f};
    for (int jt = 0; jt < 4; ++jt) {
        const int j0 = (jt * 8 + w) * 64;
        #pragma unroll
        for (int mf = 0; mf < 4; ++mf) {
            bf16x8 akf[2];
            #pragma unroll
            for (int kk = 0; kk < 2; ++kk)
                akf[kk] = *(const bf16x8*)&kT[(b * W + j0 + mf * 16 + lr) * CR + kk * 32 + (lg << 3)];
            f32x4 s[4] = {};
            #pragma unroll
            for (int kk = 0; kk < 2; ++kk)
                #pragma unroll
                for (int nf = 0; nf < 4; ++nf)
                    s[nf] = mfma16(akf[kk], bq[nf][kk], s[nf]);
            #pragma unroll
            for (int nf = 0; nf < 4; ++nf)
                #pragma unroll
                for (int r = 0; r < 4; ++r)
                    lacc[nf] += __expf(s[nf][r] * SCALE);
        }
    }
    #pragma unroll
    for (int nf = 0; nf < 4; ++nf) {
        lacc[nf] += __shfl_xor(lacc[nf], 16);
        lacc[nf] += __shfl_xor(lacc[nf], 32);
        if (lg == 0) red[w][nf * 16 + lr] = lacc[nf];
    }
    __syncthreads();
    if (t < 64) {
        float ll = 0.f;
        #pragma unroll
        for (int g = 0; g < 8; ++g) ll += red[g][t];
        ilrow[b * W + i0 + t] = 1.0f / ll;
    }
}

// ---------- context v8: block=(b, j0:32), grid 512, 8 waves, shared pt dbuf,
// raw s_barrier (counted vmcnt), deep prefetch. Wave: S 16jx16i, PV 64cx32j.
__global__ __launch_bounds__(512, 2) void context_kernel(
    const float* __restrict__ x, const ushort* __restrict__ qT, const ushort* __restrict__ kT,
    const ushort* __restrict__ v, const float* __restrict__ ilrow,
    float* __restrict__ out)
{
    __shared__ __align__(16) ushort pt[2][32][72]; // P^T [buf][j_local][i_local]
    const int bid = blockIdx.x;
    const int b = bid & 7;             // XCD-affine: one batch per XCD
    const int j0 = (bid >> 3) * 32;
    const int t = threadIdx.x;
    const int w = t >> 6, lane = t & 63;
    const int lr = lane & 15, lg = lane >> 4;
    const int jh = (w & 1) * 16;      // S^T: this wave's 16 j rows
    const int iq = (w >> 1) * 16;     // S^T: this wave's 16-i quarter
    const int c0 = w * 64;            // PV: this wave's 64 c rows
    const int NIT = W / 64;           // 32

    // kT A-frag (invariant): A[m=16j][k=d]
    bf16x8 ak[2];
    #pragma unroll
    for (int kk = 0; kk < 2; ++kk)
        ak[kk] = *(const bf16x8*)&kT[(b * W + j0 + jh + lr) * CR + kk * 32 + (lg << 3)];

    // pipeline registers
    bf16x8 av_cur[4][2], av_nxt[4][2];
    bf16x8 bq_cur[2], bq_nxt[2];
    float il_cur, il_nxt;

    #pragma unroll
    for (int mf = 0; mf < 4; ++mf)
        #pragma unroll
        for (int kk = 0; kk < 2; ++kk)
            av_cur[mf][kk] = *(const bf16x8*)&v[(b * C + c0 + mf * 16 + lr) * W + kk * 32 + (lg << 3)];

    {
        bf16x8 bq0[2];
        float il0;
        #pragma unroll
        for (int kk = 0; kk < 2; ++kk)
            bq0[kk] = *(const bf16x8*)&qT[(b * W + iq + lr) * CR + kk * 32 + (lg << 3)];
        il0 = ilrow[b * W + iq + lr];
        #pragma unroll
        for (int kk = 0; kk < 2; ++kk)
            bq_cur[kk] = *(const bf16x8*)&qT[(b * W + 64 + iq + lr) * CR + kk * 32 + (lg << 3)];
        il_cur = ilrow[b * W + 64 + iq + lr];
        // S(0) -> pt[0]
        f32x4 s = {};
        #pragma unroll
        for (int kk = 0; kk < 2; ++kk)
            s = mfma16(ak[kk], bq0[kk], s);
        #pragma unroll
        for (int r = 0; r < 4; ++r)
            pt[0][jh + (lg << 2) + r][iq + lr] = f2bs(__expf(s[r] * SCALE) * il0);
    }
    asm volatile("s_waitcnt lgkmcnt(0)" ::: "memory");
    __builtin_amdgcn_s_barrier();
    asm volatile("" ::: "memory");

    f32x4 acc[4][2] = {};
    for (int it = 0; it < NIT; ++it) {
        const int cur = it & 1;
        // ---- issue next-iter loads (counted vmcnt keeps them in flight)
        {
            const int tv = (it + 1 < NIT) ? (it + 1) : it;      // V chunk t+1
            const int tq = (it + 2 < NIT) ? (it + 2) : it;      // q/il chunk t+2
            #pragma unroll
            for (int mf = 0; mf < 4; ++mf)
                #pragma unroll
                for (int kk = 0; kk < 2; ++kk)
                    av_nxt[mf][kk] = *(const bf16x8*)&v[(b * C + c0 + mf * 16 + lr) * W + tv * 64 + kk * 32 + (lg << 3)];
            #pragma unroll
            for (int kk = 0; kk < 2; ++kk)
                bq_nxt[kk] = *(const bf16x8*)&qT[(b * W + tq * 64 + iq + lr) * CR + kk * 32 + (lg << 3)];
            il_nxt = ilrow[b * W + tq * 64 + iq + lr];
        }
        // ---- PV on pt[cur] with av_cur (loaded a full iter ago): 64c x 32j
        __builtin_amdgcn_s_setprio(1);
        #pragma unroll
        for (int kk = 0; kk < 2; ++kk) {
            bf16x8 bp[2];
            #pragma unroll
            for (int nf = 0; nf < 2; ++nf)
                bp[nf] = *(const bf16x8*)&pt[cur][nf * 16 + lr][kk * 32 + (lg << 3)];
            #pragma unroll
            for (int mf = 0; mf < 4; ++mf)
                #pragma unroll
                for (int nf = 0; nf < 2; ++nf)
                    acc[mf][nf] = mfma16(av_cur[mf][kk], bp[nf], acc[mf][nf]);
        }
        __builtin_amdgcn_s_setprio(0);
        // ---- S(it+1) -> pt[1-cur] with bq_cur (loaded a full iter ago)
        if (it + 1 < NIT) {
            f32x4 s = {};
            #pragma unroll
            for (int kk = 0; kk < 2; ++kk)
                s = mfma16(ak[kk], bq_cur[kk], s);
            #pragma unroll
            for (int r = 0; r < 4; ++r)
                pt[1 - cur][jh + (lg << 2) + r][iq + lr] =
                    f2bs(__expf(s[r] * SCALE) * il_cur);
        }
        // ---- barrier WITHOUT vmem drain: lgkm(ds) only
        asm volatile("s_waitcnt lgkmcnt(0)" ::: "memory");
        __builtin_amdgcn_s_barrier();
        asm volatile("" ::: "memory");
        // ---- rotate pipeline registers
        #pragma unroll
        for (int mf = 0; mf < 4; ++mf)
            #pragma unroll
            for (int kk = 0; kk < 2; ++kk)
                av_cur[mf][kk] = av_nxt[mf][kk];
        #pragma unroll
        for (int kk = 0; kk < 2; ++kk)
            bq_cur[kk] = bq_nxt[kk];
        il_cur = il_nxt;
    }
    // epilogue: out = acc + x
    #pragma unroll
    for (int mf = 0; mf < 4; ++mf)
        #pragma unroll
        for (int nf = 0; nf < 2; ++nf)
            #pragma unroll
            for (int r = 0; r < 4; ++r) {
                int c = c0 + mf * 16 + (lg << 2) + r;
                int j = j0 + nf * 16 + lr;
                int off = (b * C + c) * W + j;
                out[off] = acc[mf][nf][r] + x[off];
            }
}

extern "C" void kernel_launch(void* const* d_in, const int* in_sizes, int n_in,
                              void* d_out, int out_size, void* d_ws, size_t ws_size,
                              hipStream_t stream) {
    const float* x  = (const float*)d_in[0];
    const float* wq = (const float*)d_in[1];
    const float* bq = (const float*)d_in[2];
    const float* wk = (const float*)d_in[3];
    const float* bk = (const float*)d_in[4];
    const float* wv = (const float*)d_in[5];
    const float* bv = (const float*)d_in[6];
    float* out = (float*)d_out;

    char* ws = (char*)d_ws;
    ushort* qTw  = (ushort*)(ws);                                 // 2 MB
    ushort* kTw  = (ushort*)(ws + (2u << 20));                    // 2 MB
    ushort* vw   = (ushort*)(ws + (4u << 20));                    // 16 MB
    float*  ilrw = (float*)(ws + (20u << 20) + (704u << 10));     // 64 KB

    proj_qk_kernel<<<dim3(W / 64, B), 256, 0, stream>>>(x, wq, wk, bq, bk, qTw, kTw);
    proj_v_kernel<<<dim3(W / 128, C / 128, B), 256, 0, stream>>>(x, wv, bv, vw);
    stats_kernel<<<dim3(W / 64 * B), 512, 0, stream>>>(qTw, kTw, ilrw);
    context_kernel<<<dim3(W / 32 * B), 512, 0, stream>>>(x, qTw, kTw, vw, ilrw, out);
}

// Round 10
// 178.310 us; speedup vs baseline: 1.3131x; 1.3131x over previous
//
#include <hip/hip_runtime.h>
#include <hip/hip_bf16.h>

// SelfAttention: B=8, C=512, W=2048, CR=64
// NEW path (ws >= ~38.5MB): cast_w + castT(x->xb[b][w][c] bf16) ->
//   proj_qk2/proj_v2 (barrier-free direct-global MFMA GEMMs) -> stats -> context v7.
// FALLBACK path: round-8 LDS-staged proj kernels (ws <= 21MB layout).

#define B 8
#define C 512
#define W 2048
#define CR 64
static constexpr float SCALE = 0.125f; // 64^-0.5

typedef __bf16 bf16x8 __attribute__((ext_vector_type(8)));
typedef float f32x4 __attribute__((ext_vector_type(4)));

__device__ inline ushort f2bs(float f) {
    __hip_bfloat16 h = __float2bfloat16(f);
    return *reinterpret_cast<ushort*>(&h);
}
__device__ inline f32x4 mfma16(bf16x8 a, bf16x8 b, f32x4 c) {
    return __builtin_amdgcn_mfma_f32_16x16x32_bf16(a, b, c, 0, 0, 0);
}

// ================= new-path kernels =================

// cast all three weight matrices to bf16
__global__ __launch_bounds__(256) void cast_w(
    const float* __restrict__ wq, const float* __restrict__ wk, const float* __restrict__ wv,
    ushort* __restrict__ wqb, ushort* __restrict__ wkb, ushort* __restrict__ wvb)
{
    int i = blockIdx.x * 256 + threadIdx.x;
    if (i < CR * C) { wqb[i] = f2bs(wq[i]); wkb[i] = f2bs(wk[i]); }
    if (i < C * C)  { wvb[i] = f2bs(wv[i]); }
}

// x[b][c][w] fp32 -> xb[b][w][c] bf16 via LDS 64x64 transpose tile
__global__ __launch_bounds__(256) void castT_kernel(
    const float* __restrict__ x, ushort* __restrict__ xb)
{
    __shared__ __align__(16) ushort tile[64][72];
    const int b = blockIdx.z, c0 = blockIdx.y * 64, w0 = blockIdx.x * 64;
    const int t = threadIdx.x;
    for (int idx = t; idx < 64 * 64; idx += 256) {
        int c = idx >> 6, w = idx & 63;
        tile[w][c] = f2bs(x[(b * C + c0 + c) * W + w0 + w]);
    }
    __syncthreads();
    for (int idx = t; idx < 64 * 8; idx += 256) {
        int w = idx >> 3, u = idx & 7;
        *(bf16x8*)&xb[((size_t)b * W + w0 + w) * C + c0 + u * 8] = *(const bf16x8*)&tile[w][u * 8];
    }
}

// proj q+k: barrier-free. block=128thr(2 waves); wave: 32w x 64d (q & k).
// grid 1D: b=bid&7, wblk=bid>>3 (64w per block).
__global__ __launch_bounds__(128) void proj_qk2_kernel(
    const ushort* __restrict__ xb, const ushort* __restrict__ wqb, const ushort* __restrict__ wkb,
    const float* __restrict__ bqf, const float* __restrict__ bkf,
    ushort* __restrict__ qT, ushort* __restrict__ kT)
{
    const int bid = blockIdx.x;
    const int b = bid & 7;
    const int w0 = (bid >> 3) * 64 + (threadIdx.x >> 6) * 32;
    const int lane = threadIdx.x & 63;
    const int lr = lane & 15, lg = lane >> 4;

    f32x4 accq[2][4] = {};
    f32x4 acck[2][4] = {};
    for (int kk = 0; kk < 16; ++kk) {
        const int ko = kk * 32 + (lg << 3);
        bf16x8 a[2], fq[4], fk[4];
        #pragma unroll
        for (int mf = 0; mf < 2; ++mf)
            a[mf] = *(const bf16x8*)&xb[((size_t)b * W + w0 + mf * 16 + lr) * C + ko];
        #pragma unroll
        for (int nf = 0; nf < 4; ++nf) {
            fq[nf] = *(const bf16x8*)&wqb[(nf * 16 + lr) * C + ko];
            fk[nf] = *(const bf16x8*)&wkb[(nf * 16 + lr) * C + ko];
        }
        #pragma unroll
        for (int mf = 0; mf < 2; ++mf)
            #pragma unroll
            for (int nf = 0; nf < 4; ++nf) {
                accq[mf][nf] = mfma16(a[mf], fq[nf], accq[mf][nf]);
                acck[mf][nf] = mfma16(a[mf], fk[nf], acck[mf][nf]);
            }
    }
    #pragma unroll
    for (int nf = 0; nf < 4; ++nf) {
        const int d = nf * 16 + lr;
        const float bqv = bqf[d], bkv = bkf[d];
        #pragma unroll
        for (int mf = 0; mf < 2; ++mf)
            #pragma unroll
            for (int r = 0; r < 4; ++r) {
                int w = w0 + mf * 16 + (lg << 2) + r;
                qT[(b * W + w) * CR + d] = f2bs(accq[mf][nf][r] + bqv);
                kT[(b * W + w) * CR + d] = f2bs(acck[mf][nf][r] + bkv);
            }
    }
}

// proj v: barrier-free. block=512thr(8 waves: 2c x 4w); wave: 64c x 64w.
// grid 1D: b=bid&7, rest: ctile=(bid>>3)&3, wtile=bid>>5.
__global__ __launch_bounds__(512) void proj_v2_kernel(
    const ushort* __restrict__ xb, const ushort* __restrict__ wvb, const float* __restrict__ bvf,
    ushort* __restrict__ v)
{
    const int bid = blockIdx.x;
    const int b = bid & 7;
    const int ct = (bid >> 3) & 3;
    const int wt = bid >> 5;
    const int wid = threadIdx.x >> 6, lane = threadIdx.x & 63;
    const int c0 = ct * 128 + (wid >> 2) * 64;
    const int w0 = wt * 256 + (wid & 3) * 64;
    const int lr = lane & 15, lg = lane >> 4;

    f32x4 acc[4][4] = {};
    for (int kk = 0; kk < 16; ++kk) {
        const int ko = kk * 32 + (lg << 3);
        bf16x8 a[4], bb[4];
        #pragma unroll
        for (int mf = 0; mf < 4; ++mf)
            a[mf] = *(const bf16x8*)&wvb[(c0 + mf * 16 + lr) * C + ko];
        #pragma unroll
        for (int nf = 0; nf < 4; ++nf)
            bb[nf] = *(const bf16x8*)&xb[((size_t)b * W + w0 + nf * 16 + lr) * C + ko];
        #pragma unroll
        for (int mf = 0; mf < 4; ++mf)
            #pragma unroll
            for (int nf = 0; nf < 4; ++nf)
                acc[mf][nf] = mfma16(a[mf], bb[nf], acc[mf][nf]);
    }
    #pragma unroll
    for (int mf = 0; mf < 4; ++mf) {
        #pragma unroll
        for (int r = 0; r < 4; ++r) {
            const int c = c0 + mf * 16 + (lg << 2) + r;
            const float bvv = bvf[c];
            #pragma unroll
            for (int nf = 0; nf < 4; ++nf) {
                int w = w0 + nf * 16 + lr;
                v[(b * C + c) * W + w] = f2bs(acc[mf][nf][r] + bvv);
            }
        }
    }
}

// ================= fallback proj kernels (round-8, LDS-staged) =================

__global__ __launch_bounds__(256) void proj_qk_kernel(
    const float* __restrict__ x, const float* __restrict__ wqf, const float* __restrict__ wkf,
    const float* __restrict__ bq, const float* __restrict__ bk,
    ushort* __restrict__ qT, ushort* __restrict__ kT)
{
    __shared__ __align__(16) ushort xt[64][72];
    __shared__ __align__(16) ushort wq_s[64][72];
    __shared__ __align__(16) ushort wk_s[64][72];
    const int b = blockIdx.y, w0 = blockIdx.x * 64;
    const int t = threadIdx.x;
    const int wid = t >> 6, lane = t & 63;
    const int wm = wid >> 1, wn = wid & 1;
    const int lr = lane & 15, lg = lane >> 4;

    f32x4 aq[2][2] = {};
    f32x4 ak[2][2] = {};

    for (int k0 = 0; k0 < C; k0 += 64) {
        __syncthreads();
        for (int idx = t; idx < 64 * 64; idx += 256) {
            int c = idx >> 6, w = idx & 63;
            xt[w][c] = f2bs(x[(b * C + k0 + c) * W + w0 + w]);
        }
        for (int idx = t; idx < 64 * 64; idx += 256) {
            int d = idx >> 6, c = idx & 63;
            wq_s[d][c] = f2bs(wqf[d * C + k0 + c]);
            wk_s[d][c] = f2bs(wkf[d * C + k0 + c]);
        }
        __syncthreads();
        #pragma unroll
        for (int kk = 0; kk < 2; ++kk) {
            int ko = kk * 32 + (lg << 3);
            bf16x8 a[2], fq[2], fk[2];
            #pragma unroll
            for (int mf = 0; mf < 2; ++mf)
                a[mf] = *(const bf16x8*)&xt[wm * 32 + mf * 16 + lr][ko];
            #pragma unroll
            for (int nf = 0; nf < 2; ++nf) {
                fq[nf] = *(const bf16x8*)&wq_s[wn * 32 + nf * 16 + lr][ko];
                fk[nf] = *(const bf16x8*)&wk_s[wn * 32 + nf * 16 + lr][ko];
            }
            #pragma unroll
            for (int mf = 0; mf < 2; ++mf)
                #pragma unroll
                for (int nf = 0; nf < 2; ++nf) {
                    aq[mf][nf] = mfma16(a[mf], fq[nf], aq[mf][nf]);
                    ak[mf][nf] = mfma16(a[mf], fk[nf], ak[mf][nf]);
                }
        }
    }
    #pragma unroll
    for (int mf = 0; mf < 2; ++mf)
        #pragma unroll
        for (int nf = 0; nf < 2; ++nf)
            #pragma unroll
            for (int r = 0; r < 4; ++r) {
                int w = w0 + wm * 32 + mf * 16 + (lg << 2) + r;
                int d = wn * 32 + nf * 16 + lr;
                qT[(b * W + w) * CR + d] = f2bs(aq[mf][nf][r] + bq[d]);
                kT[(b * W + w) * CR + d] = f2bs(ak[mf][nf][r] + bk[d]);
            }
}

__global__ __launch_bounds__(256) void proj_v_kernel(
    const float* __restrict__ x, const float* __restrict__ wvf, const float* __restrict__ bv,
    ushort* __restrict__ v)
{
    __shared__ __align__(16) ushort wv_s[128][72];
    __shared__ __align__(16) ushort xt[128][72];
    const int b = blockIdx.z, c0 = blockIdx.y * 128, w0 = blockIdx.x * 128;
    const int t = threadIdx.x;
    const int wid = t >> 6, lane = t & 63;
    const int wm = wid >> 1, wn = wid & 1;
    const int lr = lane & 15, lg = lane >> 4;

    f32x4 acc[4][4] = {};
    for (int k0 = 0; k0 < C; k0 += 64) {
        __syncthreads();
        for (int idx = t; idx < 128 * 64; idx += 256) {
            int r = idx >> 6, c = idx & 63;
            wv_s[r][c] = f2bs(wvf[(c0 + r) * C + k0 + c]);
        }
        for (int idx = t; idx < 64 * 128; idx += 256) {
            int c = idx >> 7, w = idx & 127;
            xt[w][c] = f2bs(x[(b * C + k0 + c) * W + w0 + w]);
        }
        __syncthreads();
        #pragma unroll
        for (int kk = 0; kk < 2; ++kk) {
            int ko = kk * 32 + (lg << 3);
            bf16x8 a[4], bb[4];
            #pragma unroll
            for (int mf = 0; mf < 4; ++mf)
                a[mf] = *(const bf16x8*)&wv_s[wm * 64 + mf * 16 + lr][ko];
            #pragma unroll
            for (int nf = 0; nf < 4; ++nf)
                bb[nf] = *(const bf16x8*)&xt[wn * 64 + nf * 16 + lr][ko];
            #pragma unroll
            for (int mf = 0; mf < 4; ++mf)
                #pragma unroll
                for (int nf = 0; nf < 4; ++nf)
                    acc[mf][nf] = mfma16(a[mf], bb[nf], acc[mf][nf]);
        }
    }
    #pragma unroll
    for (int mf = 0; mf < 4; ++mf)
        #pragma unroll
        for (int nf = 0; nf < 4; ++nf)
            #pragma unroll
            for (int r = 0; r < 4; ++r) {
                int c = c0 + wm * 64 + mf * 16 + (lg << 2) + r;
                int w = w0 + wn * 64 + nf * 16 + lr;
                v[(b * C + c) * W + w] = f2bs(acc[mf][nf][r] + bv[c]);
            }
}

// ================= stats (unchanged) =================
__global__ __launch_bounds__(512) void stats_kernel(
    const ushort* __restrict__ qT, const ushort* __restrict__ kT,
    float* __restrict__ ilrow)
{
    __shared__ float red[8][64];
    const int bid = blockIdx.x;
    const int b = bid & 7;
    const int i0 = (bid >> 3) * 64;
    const int t = threadIdx.x;
    const int w = t >> 6, lane = t & 63;
    const int lr = lane & 15, lg = lane >> 4;

    bf16x8 bq[4][2];
    #pragma unroll
    for (int nf = 0; nf < 4; ++nf)
        #pragma unroll
        for (int kk = 0; kk < 2; ++kk)
            bq[nf][kk] = *(const bf16x8*)&qT[(b * W + i0 + nf * 16 + lr) * CR + kk * 32 + (lg << 3)];

    float lacc[4] = {0.f, 0.f, 0.f, 0.f};
    for (int jt = 0; jt < 4; ++jt) {
        const int j0 = (jt * 8 + w) * 64;
        #pragma unroll
        for (int mf = 0; mf < 4; ++mf) {
            bf16x8 akf[2];
            #pragma unroll
            for (int kk = 0; kk < 2; ++kk)
                akf[kk] = *(const bf16x8*)&kT[(b * W + j0 + mf * 16 + lr) * CR + kk * 32 + (lg << 3)];
            f32x4 s[4] = {};
            #pragma unroll
            for (int kk = 0; kk < 2; ++kk)
                #pragma unroll
                for (int nf = 0; nf < 4; ++nf)
                    s[nf] = mfma16(akf[kk], bq[nf][kk], s[nf]);
            #pragma unroll
            for (int nf = 0; nf < 4; ++nf)
                #pragma unroll
                for (int r = 0; r < 4; ++r)
                    lacc[nf] += __expf(s[nf][r] * SCALE);
        }
    }
    #pragma unroll
    for (int nf = 0; nf < 4; ++nf) {
        lacc[nf] += __shfl_xor(lacc[nf], 16);
        lacc[nf] += __shfl_xor(lacc[nf], 32);
        if (lg == 0) red[w][nf * 16 + lr] = lacc[nf];
    }
    __syncthreads();
    if (t < 64) {
        float ll = 0.f;
        #pragma unroll
        for (int g = 0; g < 8; ++g) ll += red[g][t];
        ilrow[b * W + i0 + t] = 1.0f / ll;
    }
}

// ================= context v7 (reverted: best known, 104us) =================
__global__ __launch_bounds__(512, 2) void context_kernel(
    const float* __restrict__ x, const ushort* __restrict__ qT, const ushort* __restrict__ kT,
    const ushort* __restrict__ v, const float* __restrict__ ilrow,
    float* __restrict__ out)
{
    __shared__ __align__(16) ushort pt[2][64][72];
    const int bid = blockIdx.x;
    const int b = bid & 7;
    const int j0 = (bid >> 3) * 64;
    const int t = threadIdx.x;
    const int w = t >> 6, lane = t & 63;
    const int lr = lane & 15, lg = lane >> 4;
    const int jsub = (w & 3) * 16;
    const int ihalf = (w >> 2) * 32;
    const int c0 = w * 64;
    const int NIT = W / 64;

    bf16x8 ak[2];
    #pragma unroll
    for (int kk = 0; kk < 2; ++kk)
        ak[kk] = *(const bf16x8*)&kT[(b * W + j0 + jsub + lr) * CR + kk * 32 + (lg << 3)];

    bf16x8 av_cur[4][2], av_nxt[4][2];
    bf16x8 bq_cur[2][2], bq_nxt[2][2];
    float il_cur[2], il_nxt[2];

    #pragma unroll
    for (int mf = 0; mf < 4; ++mf)
        #pragma unroll
        for (int kk = 0; kk < 2; ++kk)
            av_cur[mf][kk] = *(const bf16x8*)&v[(b * C + c0 + mf * 16 + lr) * W + kk * 32 + (lg << 3)];

    {
        bf16x8 bq0[2][2];
        float il0[2];
        #pragma unroll
        for (int nf = 0; nf < 2; ++nf) {
            #pragma unroll
            for (int kk = 0; kk < 2; ++kk)
                bq0[nf][kk] = *(const bf16x8*)&qT[(b * W + ihalf + nf * 16 + lr) * CR + kk * 32 + (lg << 3)];
            il0[nf] = ilrow[b * W + ihalf + nf * 16 + lr];
        }
        #pragma unroll
        for (int nf = 0; nf < 2; ++nf) {
            #pragma unroll
            for (int kk = 0; kk < 2; ++kk)
                bq_cur[nf][kk] = *(const bf16x8*)&qT[(b * W + 64 + ihalf + nf * 16 + lr) * CR + kk * 32 + (lg << 3)];
            il_cur[nf] = ilrow[b * W + 64 + ihalf + nf * 16 + lr];
        }
        f32x4 s[2] = {};
        #pragma unroll
        for (int nf = 0; nf < 2; ++nf)
            #pragma unroll
            for (int kk = 0; kk < 2; ++kk)
                s[nf] = mfma16(ak[kk], bq0[nf][kk], s[nf]);
        #pragma unroll
        for (int nf = 0; nf < 2; ++nf)
            #pragma unroll
            for (int r = 0; r < 4; ++r)
                pt[0][jsub + (lg << 2) + r][ihalf + nf * 16 + lr] =
                    f2bs(__expf(s[nf][r] * SCALE) * il0[nf]);
    }
    asm volatile("s_waitcnt lgkmcnt(0)" ::: "memory");
    __builtin_amdgcn_s_barrier();
    asm volatile("" ::: "memory");

    f32x4 acc[4][4] = {};
    for (int it = 0; it < NIT; ++it) {
        const int cur = it & 1;
        {
            const int tv = (it + 1 < NIT) ? (it + 1) : it;
            const int tq = (it + 2 < NIT) ? (it + 2) : it;
            #pragma unroll
            for (int mf = 0; mf < 4; ++mf)
                #pragma unroll
                for (int kk = 0; kk < 2; ++kk)
                    av_nxt[mf][kk] = *(const bf16x8*)&v[(b * C + c0 + mf * 16 + lr) * W + tv * 64 + kk * 32 + (lg << 3)];
            #pragma unroll
            for (int nf = 0; nf < 2; ++nf) {
                #pragma unroll
                for (int kk = 0; kk < 2; ++kk)
                    bq_nxt[nf][kk] = *(const bf16x8*)&qT[(b * W + tq * 64 + ihalf + nf * 16 + lr) * CR + kk * 32 + (lg << 3)];
                il_nxt[nf] = ilrow[b * W + tq * 64 + ihalf + nf * 16 + lr];
            }
        }
        __builtin_amdgcn_s_setprio(1);
        #pragma unroll
        for (int kk = 0; kk < 2; ++kk) {
            bf16x8 bp[4];
            #pragma unroll
            for (int nf = 0; nf < 4; ++nf)
                bp[nf] = *(const bf16x8*)&pt[cur][nf * 16 + lr][kk * 32 + (lg << 3)];
            #pragma unroll
            for (int mf = 0; mf < 4; ++mf)
                #pragma unroll
                for (int nf = 0; nf < 4; ++nf)
                    acc[mf][nf] = mfma16(av_cur[mf][kk], bp[nf], acc[mf][nf]);
        }
        __builtin_amdgcn_s_setprio(0);
        if (it + 1 < NIT) {
            f32x4 s[2] = {};
            #pragma unroll
            for (int nf = 0; nf < 2; ++nf)
                #pragma unroll
                for (int kk = 0; kk < 2; ++kk)
                    s[nf] = mfma16(ak[kk], bq_cur[nf][kk], s[nf]);
            #pragma unroll
            for (int nf = 0; nf < 2; ++nf)
                #pragma unroll
                for (int r = 0; r < 4; ++r)
                    pt[1 - cur][jsub + (lg << 2) + r][ihalf + nf * 16 + lr] =
                        f2bs(__expf(s[nf][r] * SCALE) * il_cur[nf]);
        }
        asm volatile("s_waitcnt lgkmcnt(0)" ::: "memory");
        __builtin_amdgcn_s_barrier();
        asm volatile("" ::: "memory");
        #pragma unroll
        for (int mf = 0; mf < 4; ++mf)
            #pragma unroll
            for (int kk = 0; kk < 2; ++kk)
                av_cur[mf][kk] = av_nxt[mf][kk];
        #pragma unroll
        for (int nf = 0; nf < 2; ++nf) {
            #pragma unroll
            for (int kk = 0; kk < 2; ++kk)
                bq_cur[nf][kk] = bq_nxt[nf][kk];
            il_cur[nf] = il_nxt[nf];
        }
    }
    #pragma unroll
    for (int mf = 0; mf < 4; ++mf)
        #pragma unroll
        for (int nf = 0; nf < 4; ++nf)
            #pragma unroll
            for (int r = 0; r < 4; ++r) {
                int c = c0 + mf * 16 + (lg << 2) + r;
                int j = j0 + nf * 16 + lr;
                int off = (b * C + c) * W + j;
                out[off] = acc[mf][nf][r] + x[off];
            }
}

extern "C" void kernel_launch(void* const* d_in, const int* in_sizes, int n_in,
                              void* d_out, int out_size, void* d_ws, size_t ws_size,
                              hipStream_t stream) {
    const float* x  = (const float*)d_in[0];
    const float* wq = (const float*)d_in[1];
    const float* bq = (const float*)d_in[2];
    const float* wk = (const float*)d_in[3];
    const float* bk = (const float*)d_in[4];
    const float* wv = (const float*)d_in[5];
    const float* bv = (const float*)d_in[6];
    float* out = (float*)d_out;

    char* ws = (char*)d_ws;
    ushort* qTw = (ushort*)(ws);                         // 2 MB
    ushort* kTw = (ushort*)(ws + (2u << 20));            // 2 MB
    ushort* vw  = (ushort*)(ws + (4u << 20));            // 16 MB -> ends 20MB

    const size_t NEED = ((size_t)36 << 20) + ((size_t)704 << 10);
    if (ws_size >= NEED) {
        ushort* xbw  = (ushort*)(ws + (20u << 20));                          // 16 MB -> ends 36MB
        ushort* wqb  = (ushort*)(ws + (36u << 20));                          // 64 KB
        ushort* wkb  = (ushort*)(ws + (36u << 20) + (64u << 10));            // 64 KB
        ushort* wvb  = (ushort*)(ws + (36u << 20) + (128u << 10));           // 512 KB
        float*  ilrw = (float*)(ws + (36u << 20) + (640u << 10));            // 64 KB

        cast_w<<<dim3(1024), 256, 0, stream>>>(wq, wk, wv, wqb, wkb, wvb);
        castT_kernel<<<dim3(W / 64, C / 64, B), 256, 0, stream>>>(x, xbw);
        proj_qk2_kernel<<<dim3(W / 64 * B), 128, 0, stream>>>(xbw, wqb, wkb, bq, bk, qTw, kTw);
        proj_v2_kernel<<<dim3(W / 256 * (C / 128) * B), 512, 0, stream>>>(xbw, wvb, bv, vw);
        stats_kernel<<<dim3(W / 64 * B), 512, 0, stream>>>(qTw, kTw, ilrw);
        context_kernel<<<dim3(W / 64 * B), 512, 0, stream>>>(x, qTw, kTw, vw, ilrw, out);
    } else {
        float* ilrw = (float*)(ws + (20u << 20) + (704u << 10));             // 64 KB
        proj_qk_kernel<<<dim3(W / 64, B), 256, 0, stream>>>(x, wq, wk, bq, bk, qTw, kTw);
        proj_v_kernel<<<dim3(W / 128, C / 128, B), 256, 0, stream>>>(x, wv, bv, vw);
        stats_kernel<<<dim3(W / 64 * B), 512, 0, stream>>>(qTw, kTw, ilrw);
        context_kernel<<<dim3(W / 64 * B), 512, 0, stream>>>(x, qTw, kTw, vw, ilrw, out);
    }
}

// Round 11
// 178.277 us; speedup vs baseline: 1.3133x; 1.0002x over previous
//
#include <hip/hip_runtime.h>
#include <hip/hip_bf16.h>

// SelfAttention: B=8, C=512, W=2048, CR=64
// cast_w + castT -> proj_qk2/proj_v2 (direct-global MFMA) -> stats -> context v9.
// context v9: v7 pipeline discipline (raw barrier, counted vmcnt, deep
// prefetch) with 16 waves/block (4/SIMD) for latency hiding. grid=256.

#define B 8
#define C 512
#define W 2048
#define CR 64
static constexpr float SCALE = 0.125f; // 64^-0.5

typedef __bf16 bf16x8 __attribute__((ext_vector_type(8)));
typedef float f32x4 __attribute__((ext_vector_type(4)));

__device__ inline ushort f2bs(float f) {
    __hip_bfloat16 h = __float2bfloat16(f);
    return *reinterpret_cast<ushort*>(&h);
}
__device__ inline f32x4 mfma16(bf16x8 a, bf16x8 b, f32x4 c) {
    return __builtin_amdgcn_mfma_f32_16x16x32_bf16(a, b, c, 0, 0, 0);
}

// ================= pre-pass kernels =================

__global__ __launch_bounds__(256) void cast_w(
    const float* __restrict__ wq, const float* __restrict__ wk, const float* __restrict__ wv,
    ushort* __restrict__ wqb, ushort* __restrict__ wkb, ushort* __restrict__ wvb)
{
    int i = blockIdx.x * 256 + threadIdx.x;
    if (i < CR * C) { wqb[i] = f2bs(wq[i]); wkb[i] = f2bs(wk[i]); }
    if (i < C * C)  { wvb[i] = f2bs(wv[i]); }
}

__global__ __launch_bounds__(256) void castT_kernel(
    const float* __restrict__ x, ushort* __restrict__ xb)
{
    __shared__ __align__(16) ushort tile[64][72];
    const int b = blockIdx.z, c0 = blockIdx.y * 64, w0 = blockIdx.x * 64;
    const int t = threadIdx.x;
    for (int idx = t; idx < 64 * 64; idx += 256) {
        int c = idx >> 6, w = idx & 63;
        tile[w][c] = f2bs(x[(b * C + c0 + c) * W + w0 + w]);
    }
    __syncthreads();
    for (int idx = t; idx < 64 * 8; idx += 256) {
        int w = idx >> 3, u = idx & 7;
        *(bf16x8*)&xb[((size_t)b * W + w0 + w) * C + c0 + u * 8] = *(const bf16x8*)&tile[w][u * 8];
    }
}

__global__ __launch_bounds__(128) void proj_qk2_kernel(
    const ushort* __restrict__ xb, const ushort* __restrict__ wqb, const ushort* __restrict__ wkb,
    const float* __restrict__ bqf, const float* __restrict__ bkf,
    ushort* __restrict__ qT, ushort* __restrict__ kT)
{
    const int bid = blockIdx.x;
    const int b = bid & 7;
    const int w0 = (bid >> 3) * 64 + (threadIdx.x >> 6) * 32;
    const int lane = threadIdx.x & 63;
    const int lr = lane & 15, lg = lane >> 4;

    f32x4 accq[2][4] = {};
    f32x4 acck[2][4] = {};
    for (int kk = 0; kk < 16; ++kk) {
        const int ko = kk * 32 + (lg << 3);
        bf16x8 a[2], fq[4], fk[4];
        #pragma unroll
        for (int mf = 0; mf < 2; ++mf)
            a[mf] = *(const bf16x8*)&xb[((size_t)b * W + w0 + mf * 16 + lr) * C + ko];
        #pragma unroll
        for (int nf = 0; nf < 4; ++nf) {
            fq[nf] = *(const bf16x8*)&wqb[(nf * 16 + lr) * C + ko];
            fk[nf] = *(const bf16x8*)&wkb[(nf * 16 + lr) * C + ko];
        }
        #pragma unroll
        for (int mf = 0; mf < 2; ++mf)
            #pragma unroll
            for (int nf = 0; nf < 4; ++nf) {
                accq[mf][nf] = mfma16(a[mf], fq[nf], accq[mf][nf]);
                acck[mf][nf] = mfma16(a[mf], fk[nf], acck[mf][nf]);
            }
    }
    #pragma unroll
    for (int nf = 0; nf < 4; ++nf) {
        const int d = nf * 16 + lr;
        const float bqv = bqf[d], bkv = bkf[d];
        #pragma unroll
        for (int mf = 0; mf < 2; ++mf)
            #pragma unroll
            for (int r = 0; r < 4; ++r) {
                int w = w0 + mf * 16 + (lg << 2) + r;
                qT[(b * W + w) * CR + d] = f2bs(accq[mf][nf][r] + bqv);
                kT[(b * W + w) * CR + d] = f2bs(acck[mf][nf][r] + bkv);
            }
    }
}

__global__ __launch_bounds__(512) void proj_v2_kernel(
    const ushort* __restrict__ xb, const ushort* __restrict__ wvb, const float* __restrict__ bvf,
    ushort* __restrict__ v)
{
    const int bid = blockIdx.x;
    const int b = bid & 7;
    const int ct = (bid >> 3) & 3;
    const int wt = bid >> 5;
    const int wid = threadIdx.x >> 6, lane = threadIdx.x & 63;
    const int c0 = ct * 128 + (wid >> 2) * 64;
    const int w0 = wt * 256 + (wid & 3) * 64;
    const int lr = lane & 15, lg = lane >> 4;

    f32x4 acc[4][4] = {};
    for (int kk = 0; kk < 16; ++kk) {
        const int ko = kk * 32 + (lg << 3);
        bf16x8 a[4], bb[4];
        #pragma unroll
        for (int mf = 0; mf < 4; ++mf)
            a[mf] = *(const bf16x8*)&wvb[(c0 + mf * 16 + lr) * C + ko];
        #pragma unroll
        for (int nf = 0; nf < 4; ++nf)
            bb[nf] = *(const bf16x8*)&xb[((size_t)b * W + w0 + nf * 16 + lr) * C + ko];
        #pragma unroll
        for (int mf = 0; mf < 4; ++mf)
            #pragma unroll
            for (int nf = 0; nf < 4; ++nf)
                acc[mf][nf] = mfma16(a[mf], bb[nf], acc[mf][nf]);
    }
    #pragma unroll
    for (int mf = 0; mf < 4; ++mf) {
        #pragma unroll
        for (int r = 0; r < 4; ++r) {
            const int c = c0 + mf * 16 + (lg << 2) + r;
            const float bvv = bvf[c];
            #pragma unroll
            for (int nf = 0; nf < 4; ++nf) {
                int w = w0 + nf * 16 + lr;
                v[(b * C + c) * W + w] = f2bs(acc[mf][nf][r] + bvv);
            }
        }
    }
}

// ================= fallback proj kernels (LDS-staged) =================

__global__ __launch_bounds__(256) void proj_qk_kernel(
    const float* __restrict__ x, const float* __restrict__ wqf, const float* __restrict__ wkf,
    const float* __restrict__ bq, const float* __restrict__ bk,
    ushort* __restrict__ qT, ushort* __restrict__ kT)
{
    __shared__ __align__(16) ushort xt[64][72];
    __shared__ __align__(16) ushort wq_s[64][72];
    __shared__ __align__(16) ushort wk_s[64][72];
    const int b = blockIdx.y, w0 = blockIdx.x * 64;
    const int t = threadIdx.x;
    const int wid = t >> 6, lane = t & 63;
    const int wm = wid >> 1, wn = wid & 1;
    const int lr = lane & 15, lg = lane >> 4;

    f32x4 aq[2][2] = {};
    f32x4 ak[2][2] = {};

    for (int k0 = 0; k0 < C; k0 += 64) {
        __syncthreads();
        for (int idx = t; idx < 64 * 64; idx += 256) {
            int c = idx >> 6, w = idx & 63;
            xt[w][c] = f2bs(x[(b * C + k0 + c) * W + w0 + w]);
        }
        for (int idx = t; idx < 64 * 64; idx += 256) {
            int d = idx >> 6, c = idx & 63;
            wq_s[d][c] = f2bs(wqf[d * C + k0 + c]);
            wk_s[d][c] = f2bs(wkf[d * C + k0 + c]);
        }
        __syncthreads();
        #pragma unroll
        for (int kk = 0; kk < 2; ++kk) {
            int ko = kk * 32 + (lg << 3);
            bf16x8 a[2], fq[2], fk[2];
            #pragma unroll
            for (int mf = 0; mf < 2; ++mf)
                a[mf] = *(const bf16x8*)&xt[wm * 32 + mf * 16 + lr][ko];
            #pragma unroll
            for (int nf = 0; nf < 2; ++nf) {
                fq[nf] = *(const bf16x8*)&wq_s[wn * 32 + nf * 16 + lr][ko];
                fk[nf] = *(const bf16x8*)&wk_s[wn * 32 + nf * 16 + lr][ko];
            }
            #pragma unroll
            for (int mf = 0; mf < 2; ++mf)
                #pragma unroll
                for (int nf = 0; nf < 2; ++nf) {
                    aq[mf][nf] = mfma16(a[mf], fq[nf], aq[mf][nf]);
                    ak[mf][nf] = mfma16(a[mf], fk[nf], ak[mf][nf]);
                }
        }
    }
    #pragma unroll
    for (int mf = 0; mf < 2; ++mf)
        #pragma unroll
        for (int nf = 0; nf < 2; ++nf)
            #pragma unroll
            for (int r = 0; r < 4; ++r) {
                int w = w0 + wm * 32 + mf * 16 + (lg << 2) + r;
                int d = wn * 32 + nf * 16 + lr;
                qT[(b * W + w) * CR + d] = f2bs(aq[mf][nf][r] + bq[d]);
                kT[(b * W + w) * CR + d] = f2bs(ak[mf][nf][r] + bk[d]);
            }
}

__global__ __launch_bounds__(256) void proj_v_kernel(
    const float* __restrict__ x, const float* __restrict__ wvf, const float* __restrict__ bv,
    ushort* __restrict__ v)
{
    __shared__ __align__(16) ushort wv_s[128][72];
    __shared__ __align__(16) ushort xt[128][72];
    const int b = blockIdx.z, c0 = blockIdx.y * 128, w0 = blockIdx.x * 128;
    const int t = threadIdx.x;
    const int wid = t >> 6, lane = t & 63;
    const int wm = wid >> 1, wn = wid & 1;
    const int lr = lane & 15, lg = lane >> 4;

    f32x4 acc[4][4] = {};
    for (int k0 = 0; k0 < C; k0 += 64) {
        __syncthreads();
        for (int idx = t; idx < 128 * 64; idx += 256) {
            int r = idx >> 6, c = idx & 63;
            wv_s[r][c] = f2bs(wvf[(c0 + r) * C + k0 + c]);
        }
        for (int idx = t; idx < 64 * 128; idx += 256) {
            int c = idx >> 7, w = idx & 127;
            xt[w][c] = f2bs(x[(b * C + k0 + c) * W + w0 + w]);
        }
        __syncthreads();
        #pragma unroll
        for (int kk = 0; kk < 2; ++kk) {
            int ko = kk * 32 + (lg << 3);
            bf16x8 a[4], bb[4];
            #pragma unroll
            for (int mf = 0; mf < 4; ++mf)
                a[mf] = *(const bf16x8*)&wv_s[wm * 64 + mf * 16 + lr][ko];
            #pragma unroll
            for (int nf = 0; nf < 4; ++nf)
                bb[nf] = *(const bf16x8*)&xt[wn * 64 + nf * 16 + lr][ko];
            #pragma unroll
            for (int mf = 0; mf < 4; ++mf)
                #pragma unroll
                for (int nf = 0; nf < 4; ++nf)
                    acc[mf][nf] = mfma16(a[mf], bb[nf], acc[mf][nf]);
        }
    }
    #pragma unroll
    for (int mf = 0; mf < 4; ++mf)
        #pragma unroll
        for (int nf = 0; nf < 4; ++nf)
            #pragma unroll
            for (int r = 0; r < 4; ++r) {
                int c = c0 + wm * 64 + mf * 16 + (lg << 2) + r;
                int w = w0 + wn * 64 + nf * 16 + lr;
                v[(b * C + c) * W + w] = f2bs(acc[mf][nf][r] + bv[c]);
            }
}

// ================= stats (unchanged) =================
__global__ __launch_bounds__(512) void stats_kernel(
    const ushort* __restrict__ qT, const ushort* __restrict__ kT,
    float* __restrict__ ilrow)
{
    __shared__ float red[8][64];
    const int bid = blockIdx.x;
    const int b = bid & 7;
    const int i0 = (bid >> 3) * 64;
    const int t = threadIdx.x;
    const int w = t >> 6, lane = t & 63;
    const int lr = lane & 15, lg = lane >> 4;

    bf16x8 bq[4][2];
    #pragma unroll
    for (int nf = 0; nf < 4; ++nf)
        #pragma unroll
        for (int kk = 0; kk < 2; ++kk)
            bq[nf][kk] = *(const bf16x8*)&qT[(b * W + i0 + nf * 16 + lr) * CR + kk * 32 + (lg << 3)];

    float lacc[4] = {0.f, 0.f, 0.f, 0.f};
    for (int jt = 0; jt < 4; ++jt) {
        const int j0 = (jt * 8 + w) * 64;
        #pragma unroll
        for (int mf = 0; mf < 4; ++mf) {
            bf16x8 akf[2];
            #pragma unroll
            for (int kk = 0; kk < 2; ++kk)
                akf[kk] = *(const bf16x8*)&kT[(b * W + j0 + mf * 16 + lr) * CR + kk * 32 + (lg << 3)];
            f32x4 s[4] = {};
            #pragma unroll
            for (int kk = 0; kk < 2; ++kk)
                #pragma unroll
                for (int nf = 0; nf < 4; ++nf)
                    s[nf] = mfma16(akf[kk], bq[nf][kk], s[nf]);
            #pragma unroll
            for (int nf = 0; nf < 4; ++nf)
                #pragma unroll
                for (int r = 0; r < 4; ++r)
                    lacc[nf] += __expf(s[nf][r] * SCALE);
        }
    }
    #pragma unroll
    for (int nf = 0; nf < 4; ++nf) {
        lacc[nf] += __shfl_xor(lacc[nf], 16);
        lacc[nf] += __shfl_xor(lacc[nf], 32);
        if (lg == 0) red[w][nf * 16 + lr] = lacc[nf];
    }
    __syncthreads();
    if (t < 64) {
        float ll = 0.f;
        #pragma unroll
        for (int g = 0; g < 8; ++g) ll += red[g][t];
        ilrow[b * W + i0 + t] = 1.0f / ll;
    }
}

// ================= context v9: 16 waves (4/SIMD), v7 discipline =================
// block=(b, j0:64), 1024 thr. Wave w: S = 16j x 16i (jq=(w&3)*16, iq=(w>>2)*16);
// PV = 32c x 64j (c0=w*32). Shared pt dbuf, raw barrier, deep prefetch.
__global__ __launch_bounds__(1024) void context_kernel(
    const float* __restrict__ x, const ushort* __restrict__ qT, const ushort* __restrict__ kT,
    const ushort* __restrict__ v, const float* __restrict__ ilrow,
    float* __restrict__ out)
{
    __shared__ __align__(16) ushort pt[2][64][72];
    const int bid = blockIdx.x;
    const int b = bid & 7;
    const int j0 = (bid >> 3) * 64;
    const int t = threadIdx.x;
    const int w = t >> 6, lane = t & 63;
    const int lr = lane & 15, lg = lane >> 4;
    const int jq = (w & 3) * 16;   // S: this wave's 16 j rows
    const int iq = (w >> 2) * 16;  // S: this wave's 16 i cols
    const int c0 = w * 32;         // PV: this wave's 32 c rows
    const int NIT = W / 64;

    // kT A-frag (invariant)
    bf16x8 ak[2];
    #pragma unroll
    for (int kk = 0; kk < 2; ++kk)
        ak[kk] = *(const bf16x8*)&kT[(b * W + j0 + jq + lr) * CR + kk * 32 + (lg << 3)];

    bf16x8 av_cur[2][2], av_nxt[2][2];
    bf16x8 bq_cur[2], bq_nxt[2];
    float il_cur, il_nxt;

    #pragma unroll
    for (int mf = 0; mf < 2; ++mf)
        #pragma unroll
        for (int kk = 0; kk < 2; ++kk)
            av_cur[mf][kk] = *(const bf16x8*)&v[(b * C + c0 + mf * 16 + lr) * W + kk * 32 + (lg << 3)];

    {
        bf16x8 bq0[2];
        float il0;
        #pragma unroll
        for (int kk = 0; kk < 2; ++kk)
            bq0[kk] = *(const bf16x8*)&qT[(b * W + iq + lr) * CR + kk * 32 + (lg << 3)];
        il0 = ilrow[b * W + iq + lr];
        #pragma unroll
        for (int kk = 0; kk < 2; ++kk)
            bq_cur[kk] = *(const bf16x8*)&qT[(b * W + 64 + iq + lr) * CR + kk * 32 + (lg << 3)];
        il_cur = ilrow[b * W + 64 + iq + lr];
        // S(0) -> pt[0]
        f32x4 s = {};
        #pragma unroll
        for (int kk = 0; kk < 2; ++kk)
            s = mfma16(ak[kk], bq0[kk], s);
        #pragma unroll
        for (int r = 0; r < 4; ++r)
            pt[0][jq + (lg << 2) + r][iq + lr] = f2bs(__expf(s[r] * SCALE) * il0);
    }
    asm volatile("s_waitcnt lgkmcnt(0)" ::: "memory");
    __builtin_amdgcn_s_barrier();
    asm volatile("" ::: "memory");

    f32x4 acc[2][4] = {};
    for (int it = 0; it < NIT; ++it) {
        const int cur = it & 1;
        // ---- issue next-iter loads (counted vmcnt keeps them in flight)
        {
            const int tv = (it + 1 < NIT) ? (it + 1) : it;
            const int tq = (it + 2 < NIT) ? (it + 2) : it;
            #pragma unroll
            for (int mf = 0; mf < 2; ++mf)
                #pragma unroll
                for (int kk = 0; kk < 2; ++kk)
                    av_nxt[mf][kk] = *(const bf16x8*)&v[(b * C + c0 + mf * 16 + lr) * W + tv * 64 + kk * 32 + (lg << 3)];
            #pragma unroll
            for (int kk = 0; kk < 2; ++kk)
                bq_nxt[kk] = *(const bf16x8*)&qT[(b * W + tq * 64 + iq + lr) * CR + kk * 32 + (lg << 3)];
            il_nxt = ilrow[b * W + tq * 64 + iq + lr];
        }
        // ---- PV on pt[cur] with av_cur: 32c x 64j, K=64
        __builtin_amdgcn_s_setprio(1);
        #pragma unroll
        for (int kk = 0; kk < 2; ++kk) {
            bf16x8 bp[4];
            #pragma unroll
            for (int nf = 0; nf < 4; ++nf)
                bp[nf] = *(const bf16x8*)&pt[cur][nf * 16 + lr][kk * 32 + (lg << 3)];
            #pragma unroll
            for (int mf = 0; mf < 2; ++mf)
                #pragma unroll
                for (int nf = 0; nf < 4; ++nf)
                    acc[mf][nf] = mfma16(av_cur[mf][kk], bp[nf], acc[mf][nf]);
        }
        __builtin_amdgcn_s_setprio(0);
        // ---- S(it+1) -> pt[1-cur] with bq_cur
        if (it + 1 < NIT) {
            f32x4 s = {};
            #pragma unroll
            for (int kk = 0; kk < 2; ++kk)
                s = mfma16(ak[kk], bq_cur[kk], s);
            #pragma unroll
            for (int r = 0; r < 4; ++r)
                pt[1 - cur][jq + (lg << 2) + r][iq + lr] =
                    f2bs(__expf(s[r] * SCALE) * il_cur);
        }
        // ---- barrier WITHOUT vmem drain
        asm volatile("s_waitcnt lgkmcnt(0)" ::: "memory");
        __builtin_amdgcn_s_barrier();
        asm volatile("" ::: "memory");
        // ---- rotate pipeline registers
        #pragma unroll
        for (int mf = 0; mf < 2; ++mf)
            #pragma unroll
            for (int kk = 0; kk < 2; ++kk)
                av_cur[mf][kk] = av_nxt[mf][kk];
        #pragma unroll
        for (int kk = 0; kk < 2; ++kk)
            bq_cur[kk] = bq_nxt[kk];
        il_cur = il_nxt;
    }
    // epilogue: out = acc + x
    #pragma unroll
    for (int mf = 0; mf < 2; ++mf)
        #pragma unroll
        for (int nf = 0; nf < 4; ++nf)
            #pragma unroll
            for (int r = 0; r < 4; ++r) {
                int c = c0 + mf * 16 + (lg << 2) + r;
                int j = j0 + nf * 16 + lr;
                int off = (b * C + c) * W + j;
                out[off] = acc[mf][nf][r] + x[off];
            }
}

extern "C" void kernel_launch(void* const* d_in, const int* in_sizes, int n_in,
                              void* d_out, int out_size, void* d_ws, size_t ws_size,
                              hipStream_t stream) {
    const float* x  = (const float*)d_in[0];
    const float* wq = (const float*)d_in[1];
    const float* bq = (const float*)d_in[2];
    const float* wk = (const float*)d_in[3];
    const float* bk = (const float*)d_in[4];
    const float* wv = (const float*)d_in[5];
    const float* bv = (const float*)d_in[6];
    float* out = (float*)d_out;

    char* ws = (char*)d_ws;
    ushort* qTw = (ushort*)(ws);                         // 2 MB
    ushort* kTw = (ushort*)(ws + (2u << 20));            // 2 MB
    ushort* vw  = (ushort*)(ws + (4u << 20));            // 16 MB -> ends 20MB

    const size_t NEED = ((size_t)36 << 20) + ((size_t)704 << 10);
    if (ws_size >= NEED) {
        ushort* xbw  = (ushort*)(ws + (20u << 20));
        ushort* wqb  = (ushort*)(ws + (36u << 20));
        ushort* wkb  = (ushort*)(ws + (36u << 20) + (64u << 10));
        ushort* wvb  = (ushort*)(ws + (36u << 20) + (128u << 10));
        float*  ilrw = (float*)(ws + (36u << 20) + (640u << 10));

        cast_w<<<dim3(1024), 256, 0, stream>>>(wq, wk, wv, wqb, wkb, wvb);
        castT_kernel<<<dim3(W / 64, C / 64, B), 256, 0, stream>>>(x, xbw);
        proj_qk2_kernel<<<dim3(W / 64 * B), 128, 0, stream>>>(xbw, wqb, wkb, bq, bk, qTw, kTw);
        proj_v2_kernel<<<dim3(W / 256 * (C / 128) * B), 512, 0, stream>>>(xbw, wvb, bv, vw);
        stats_kernel<<<dim3(W / 64 * B), 512, 0, stream>>>(qTw, kTw, ilrw);
        context_kernel<<<dim3(W / 64 * B), 1024, 0, stream>>>(x, qTw, kTw, vw, ilrw, out);
    } else {
        float* ilrw = (float*)(ws + (20u << 20) + (704u << 10));
        proj_qk_kernel<<<dim3(W / 64, B), 256, 0, stream>>>(x, wq, wk, bq, bk, qTw, kTw);
        proj_v_kernel<<<dim3(W / 128, C / 128, B), 256, 0, stream>>>(x, wv, bv, vw);
        stats_kernel<<<dim3(W / 64 * B), 512, 0, stream>>>(qTw, kTw, ilrw);
        context_kernel<<<dim3(W / 64 * B), 1024, 0, stream>>>(x, qTw, kTw, vw, ilrw, out);
    }
}

// Round 12
// 177.841 us; speedup vs baseline: 1.3165x; 1.0024x over previous
//
#include <hip/hip_runtime.h>
#include <hip/hip_bf16.h>

// SelfAttention: B=8, C=512, W=2048, CR=64
// cast_w + castT -> proj_qk2/proj_v2 -> stats -> context v10.
// context v10: wave specialization. Block=(b, j64), 768 thr = 12 waves:
//   waves 0-3  (producers): S^T(t+1) MFMA + exp + pt[1-cur] writes
//   waves 4-11 (consumers): PV(t) from pt[cur], 64c each, acc in regs
// Phases overlap on different pipes each iter; raw barrier, no vmem drain.

#define B 8
#define C 512
#define W 2048
#define CR 64
static constexpr float SCALE = 0.125f; // 64^-0.5

typedef __bf16 bf16x8 __attribute__((ext_vector_type(8)));
typedef float f32x4 __attribute__((ext_vector_type(4)));

__device__ inline ushort f2bs(float f) {
    __hip_bfloat16 h = __float2bfloat16(f);
    return *reinterpret_cast<ushort*>(&h);
}
__device__ inline f32x4 mfma16(bf16x8 a, bf16x8 b, f32x4 c) {
    return __builtin_amdgcn_mfma_f32_16x16x32_bf16(a, b, c, 0, 0, 0);
}

// ================= pre-pass kernels =================

__global__ __launch_bounds__(256) void cast_w(
    const float* __restrict__ wq, const float* __restrict__ wk, const float* __restrict__ wv,
    ushort* __restrict__ wqb, ushort* __restrict__ wkb, ushort* __restrict__ wvb)
{
    int i = blockIdx.x * 256 + threadIdx.x;
    if (i < CR * C) { wqb[i] = f2bs(wq[i]); wkb[i] = f2bs(wk[i]); }
    if (i < C * C)  { wvb[i] = f2bs(wv[i]); }
}

__global__ __launch_bounds__(256) void castT_kernel(
    const float* __restrict__ x, ushort* __restrict__ xb)
{
    __shared__ __align__(16) ushort tile[64][72];
    const int b = blockIdx.z, c0 = blockIdx.y * 64, w0 = blockIdx.x * 64;
    const int t = threadIdx.x;
    for (int idx = t; idx < 64 * 64; idx += 256) {
        int c = idx >> 6, w = idx & 63;
        tile[w][c] = f2bs(x[(b * C + c0 + c) * W + w0 + w]);
    }
    __syncthreads();
    for (int idx = t; idx < 64 * 8; idx += 256) {
        int w = idx >> 3, u = idx & 7;
        *(bf16x8*)&xb[((size_t)b * W + w0 + w) * C + c0 + u * 8] = *(const bf16x8*)&tile[w][u * 8];
    }
}

__global__ __launch_bounds__(128) void proj_qk2_kernel(
    const ushort* __restrict__ xb, const ushort* __restrict__ wqb, const ushort* __restrict__ wkb,
    const float* __restrict__ bqf, const float* __restrict__ bkf,
    ushort* __restrict__ qT, ushort* __restrict__ kT)
{
    const int bid = blockIdx.x;
    const int b = bid & 7;
    const int w0 = (bid >> 3) * 64 + (threadIdx.x >> 6) * 32;
    const int lane = threadIdx.x & 63;
    const int lr = lane & 15, lg = lane >> 4;

    f32x4 accq[2][4] = {};
    f32x4 acck[2][4] = {};
    for (int kk = 0; kk < 16; ++kk) {
        const int ko = kk * 32 + (lg << 3);
        bf16x8 a[2], fq[4], fk[4];
        #pragma unroll
        for (int mf = 0; mf < 2; ++mf)
            a[mf] = *(const bf16x8*)&xb[((size_t)b * W + w0 + mf * 16 + lr) * C + ko];
        #pragma unroll
        for (int nf = 0; nf < 4; ++nf) {
            fq[nf] = *(const bf16x8*)&wqb[(nf * 16 + lr) * C + ko];
            fk[nf] = *(const bf16x8*)&wkb[(nf * 16 + lr) * C + ko];
        }
        #pragma unroll
        for (int mf = 0; mf < 2; ++mf)
            #pragma unroll
            for (int nf = 0; nf < 4; ++nf) {
                accq[mf][nf] = mfma16(a[mf], fq[nf], accq[mf][nf]);
                acck[mf][nf] = mfma16(a[mf], fk[nf], acck[mf][nf]);
            }
    }
    #pragma unroll
    for (int nf = 0; nf < 4; ++nf) {
        const int d = nf * 16 + lr;
        const float bqv = bqf[d], bkv = bkf[d];
        #pragma unroll
        for (int mf = 0; mf < 2; ++mf)
            #pragma unroll
            for (int r = 0; r < 4; ++r) {
                int w = w0 + mf * 16 + (lg << 2) + r;
                qT[(b * W + w) * CR + d] = f2bs(accq[mf][nf][r] + bqv);
                kT[(b * W + w) * CR + d] = f2bs(acck[mf][nf][r] + bkv);
            }
    }
}

__global__ __launch_bounds__(512) void proj_v2_kernel(
    const ushort* __restrict__ xb, const ushort* __restrict__ wvb, const float* __restrict__ bvf,
    ushort* __restrict__ v)
{
    const int bid = blockIdx.x;
    const int b = bid & 7;
    const int ct = (bid >> 3) & 3;
    const int wt = bid >> 5;
    const int wid = threadIdx.x >> 6, lane = threadIdx.x & 63;
    const int c0 = ct * 128 + (wid >> 2) * 64;
    const int w0 = wt * 256 + (wid & 3) * 64;
    const int lr = lane & 15, lg = lane >> 4;

    f32x4 acc[4][4] = {};
    for (int kk = 0; kk < 16; ++kk) {
        const int ko = kk * 32 + (lg << 3);
        bf16x8 a[4], bb[4];
        #pragma unroll
        for (int mf = 0; mf < 4; ++mf)
            a[mf] = *(const bf16x8*)&wvb[(c0 + mf * 16 + lr) * C + ko];
        #pragma unroll
        for (int nf = 0; nf < 4; ++nf)
            bb[nf] = *(const bf16x8*)&xb[((size_t)b * W + w0 + nf * 16 + lr) * C + ko];
        #pragma unroll
        for (int mf = 0; mf < 4; ++mf)
            #pragma unroll
            for (int nf = 0; nf < 4; ++nf)
                acc[mf][nf] = mfma16(a[mf], bb[nf], acc[mf][nf]);
    }
    #pragma unroll
    for (int mf = 0; mf < 4; ++mf) {
        #pragma unroll
        for (int r = 0; r < 4; ++r) {
            const int c = c0 + mf * 16 + (lg << 2) + r;
            const float bvv = bvf[c];
            #pragma unroll
            for (int nf = 0; nf < 4; ++nf) {
                int w = w0 + nf * 16 + lr;
                v[(b * C + c) * W + w] = f2bs(acc[mf][nf][r] + bvv);
            }
        }
    }
}

// ================= fallback proj kernels (LDS-staged) =================

__global__ __launch_bounds__(256) void proj_qk_kernel(
    const float* __restrict__ x, const float* __restrict__ wqf, const float* __restrict__ wkf,
    const float* __restrict__ bq, const float* __restrict__ bk,
    ushort* __restrict__ qT, ushort* __restrict__ kT)
{
    __shared__ __align__(16) ushort xt[64][72];
    __shared__ __align__(16) ushort wq_s[64][72];
    __shared__ __align__(16) ushort wk_s[64][72];
    const int b = blockIdx.y, w0 = blockIdx.x * 64;
    const int t = threadIdx.x;
    const int wid = t >> 6, lane = t & 63;
    const int wm = wid >> 1, wn = wid & 1;
    const int lr = lane & 15, lg = lane >> 4;

    f32x4 aq[2][2] = {};
    f32x4 ak[2][2] = {};

    for (int k0 = 0; k0 < C; k0 += 64) {
        __syncthreads();
        for (int idx = t; idx < 64 * 64; idx += 256) {
            int c = idx >> 6, w = idx & 63;
            xt[w][c] = f2bs(x[(b * C + k0 + c) * W + w0 + w]);
        }
        for (int idx = t; idx < 64 * 64; idx += 256) {
            int d = idx >> 6, c = idx & 63;
            wq_s[d][c] = f2bs(wqf[d * C + k0 + c]);
            wk_s[d][c] = f2bs(wkf[d * C + k0 + c]);
        }
        __syncthreads();
        #pragma unroll
        for (int kk = 0; kk < 2; ++kk) {
            int ko = kk * 32 + (lg << 3);
            bf16x8 a[2], fq[2], fk[2];
            #pragma unroll
            for (int mf = 0; mf < 2; ++mf)
                a[mf] = *(const bf16x8*)&xt[wm * 32 + mf * 16 + lr][ko];
            #pragma unroll
            for (int nf = 0; nf < 2; ++nf) {
                fq[nf] = *(const bf16x8*)&wq_s[wn * 32 + nf * 16 + lr][ko];
                fk[nf] = *(const bf16x8*)&wk_s[wn * 32 + nf * 16 + lr][ko];
            }
            #pragma unroll
            for (int mf = 0; mf < 2; ++mf)
                #pragma unroll
                for (int nf = 0; nf < 2; ++nf) {
                    aq[mf][nf] = mfma16(a[mf], fq[nf], aq[mf][nf]);
                    ak[mf][nf] = mfma16(a[mf], fk[nf], ak[mf][nf]);
                }
        }
    }
    #pragma unroll
    for (int mf = 0; mf < 2; ++mf)
        #pragma unroll
        for (int nf = 0; nf < 2; ++nf)
            #pragma unroll
            for (int r = 0; r < 4; ++r) {
                int w = w0 + wm * 32 + mf * 16 + (lg << 2) + r;
                int d = wn * 32 + nf * 16 + lr;
                qT[(b * W + w) * CR + d] = f2bs(aq[mf][nf][r] + bq[d]);
                kT[(b * W + w) * CR + d] = f2bs(ak[mf][nf][r] + bk[d]);
            }
}

__global__ __launch_bounds__(256) void proj_v_kernel(
    const float* __restrict__ x, const float* __restrict__ wvf, const float* __restrict__ bv,
    ushort* __restrict__ v)
{
    __shared__ __align__(16) ushort wv_s[128][72];
    __shared__ __align__(16) ushort xt[128][72];
    const int b = blockIdx.z, c0 = blockIdx.y * 128, w0 = blockIdx.x * 128;
    const int t = threadIdx.x;
    const int wid = t >> 6, lane = t & 63;
    const int wm = wid >> 1, wn = wid & 1;
    const int lr = lane & 15, lg = lane >> 4;

    f32x4 acc[4][4] = {};
    for (int k0 = 0; k0 < C; k0 += 64) {
        __syncthreads();
        for (int idx = t; idx < 128 * 64; idx += 256) {
            int r = idx >> 6, c = idx & 63;
            wv_s[r][c] = f2bs(wvf[(c0 + r) * C + k0 + c]);
        }
        for (int idx = t; idx < 64 * 128; idx += 256) {
            int c = idx >> 7, w = idx & 127;
            xt[w][c] = f2bs(x[(b * C + k0 + c) * W + w0 + w]);
        }
        __syncthreads();
        #pragma unroll
        for (int kk = 0; kk < 2; ++kk) {
            int ko = kk * 32 + (lg << 3);
            bf16x8 a[4], bb[4];
            #pragma unroll
            for (int mf = 0; mf < 4; ++mf)
                a[mf] = *(const bf16x8*)&wv_s[wm * 64 + mf * 16 + lr][ko];
            #pragma unroll
            for (int nf = 0; nf < 4; ++nf)
                bb[nf] = *(const bf16x8*)&xt[wn * 64 + nf * 16 + lr][ko];
            #pragma unroll
            for (int mf = 0; mf < 4; ++mf)
                #pragma unroll
                for (int nf = 0; nf < 4; ++nf)
                    acc[mf][nf] = mfma16(a[mf], bb[nf], acc[mf][nf]);
        }
    }
    #pragma unroll
    for (int mf = 0; mf < 4; ++mf)
        #pragma unroll
        for (int nf = 0; nf < 4; ++nf)
            #pragma unroll
            for (int r = 0; r < 4; ++r) {
                int c = c0 + wm * 64 + mf * 16 + (lg << 2) + r;
                int w = w0 + wn * 64 + nf * 16 + lr;
                v[(b * C + c) * W + w] = f2bs(acc[mf][nf][r] + bv[c]);
            }
}

// ================= stats (unchanged) =================
__global__ __launch_bounds__(512) void stats_kernel(
    const ushort* __restrict__ qT, const ushort* __restrict__ kT,
    float* __restrict__ ilrow)
{
    __shared__ float red[8][64];
    const int bid = blockIdx.x;
    const int b = bid & 7;
    const int i0 = (bid >> 3) * 64;
    const int t = threadIdx.x;
    const int w = t >> 6, lane = t & 63;
    const int lr = lane & 15, lg = lane >> 4;

    bf16x8 bq[4][2];
    #pragma unroll
    for (int nf = 0; nf < 4; ++nf)
        #pragma unroll
        for (int kk = 0; kk < 2; ++kk)
            bq[nf][kk] = *(const bf16x8*)&qT[(b * W + i0 + nf * 16 + lr) * CR + kk * 32 + (lg << 3)];

    float lacc[4] = {0.f, 0.f, 0.f, 0.f};
    for (int jt = 0; jt < 4; ++jt) {
        const int j0 = (jt * 8 + w) * 64;
        #pragma unroll
        for (int mf = 0; mf < 4; ++mf) {
            bf16x8 akf[2];
            #pragma unroll
            for (int kk = 0; kk < 2; ++kk)
                akf[kk] = *(const bf16x8*)&kT[(b * W + j0 + mf * 16 + lr) * CR + kk * 32 + (lg << 3)];
            f32x4 s[4] = {};
            #pragma unroll
            for (int kk = 0; kk < 2; ++kk)
                #pragma unroll
                for (int nf = 0; nf < 4; ++nf)
                    s[nf] = mfma16(akf[kk], bq[nf][kk], s[nf]);
            #pragma unroll
            for (int nf = 0; nf < 4; ++nf)
                #pragma unroll
                for (int r = 0; r < 4; ++r)
                    lacc[nf] += __expf(s[nf][r] * SCALE);
        }
    }
    #pragma unroll
    for (int nf = 0; nf < 4; ++nf) {
        lacc[nf] += __shfl_xor(lacc[nf], 16);
        lacc[nf] += __shfl_xor(lacc[nf], 32);
        if (lg == 0) red[w][nf * 16 + lr] = lacc[nf];
    }
    __syncthreads();
    if (t < 64) {
        float ll = 0.f;
        #pragma unroll
        for (int g = 0; g < 8; ++g) ll += red[g][t];
        ilrow[b * W + i0 + t] = 1.0f / ll;
    }
}

// ================= context v10: producer/consumer wave specialization ======
__global__ __launch_bounds__(768, 1) void context_kernel(
    const float* __restrict__ x, const ushort* __restrict__ qT, const ushort* __restrict__ kT,
    const ushort* __restrict__ v, const float* __restrict__ ilrow,
    float* __restrict__ out)
{
    __shared__ __align__(16) ushort pt[2][64][72];
    const int bid = blockIdx.x;
    const int b = bid & 7;
    const int j0 = (bid >> 3) * 64;
    const int t = threadIdx.x;
    const int w = t >> 6, lane = t & 63;
    const int lr = lane & 15, lg = lane >> 4;
    const int NIT = W / 64;

    if (w < 4) {
        // ---------- producer: 16 j rows (jp), all 64 i per chunk ----------
        const int jp = w * 16;
        bf16x8 ak[2];
        #pragma unroll
        for (int kk = 0; kk < 2; ++kk)
            ak[kk] = *(const bf16x8*)&kT[(b * W + j0 + jp + lr) * CR + kk * 32 + (lg << 3)];

        bf16x8 bq_cur[4][2], bq_nxt[4][2];
        float il_cur[4], il_nxt[4];
        {
            bf16x8 bq0[4][2];
            float il0[4];
            #pragma unroll
            for (int nf = 0; nf < 4; ++nf) {
                #pragma unroll
                for (int kk = 0; kk < 2; ++kk)
                    bq0[nf][kk] = *(const bf16x8*)&qT[(b * W + nf * 16 + lr) * CR + kk * 32 + (lg << 3)];
                il0[nf] = ilrow[b * W + nf * 16 + lr];
            }
            #pragma unroll
            for (int nf = 0; nf < 4; ++nf) {
                #pragma unroll
                for (int kk = 0; kk < 2; ++kk)
                    bq_cur[nf][kk] = *(const bf16x8*)&qT[(b * W + 64 + nf * 16 + lr) * CR + kk * 32 + (lg << 3)];
                il_cur[nf] = ilrow[b * W + 64 + nf * 16 + lr];
            }
            // S(0) -> pt[0]
            #pragma unroll
            for (int nf = 0; nf < 4; ++nf) {
                f32x4 s = {};
                #pragma unroll
                for (int kk = 0; kk < 2; ++kk)
                    s = mfma16(ak[kk], bq0[nf][kk], s);
                #pragma unroll
                for (int r = 0; r < 4; ++r)
                    pt[0][jp + (lg << 2) + r][nf * 16 + lr] =
                        f2bs(__expf(s[r] * SCALE) * il0[nf]);
            }
        }
        asm volatile("s_waitcnt lgkmcnt(0)" ::: "memory");
        __builtin_amdgcn_s_barrier();
        asm volatile("" ::: "memory");

        for (int it = 0; it < NIT; ++it) {
            const int cur = it & 1;
            const int tq = (it + 2 < NIT) ? (it + 2) : it;
            #pragma unroll
            for (int nf = 0; nf < 4; ++nf) {
                #pragma unroll
                for (int kk = 0; kk < 2; ++kk)
                    bq_nxt[nf][kk] = *(const bf16x8*)&qT[(b * W + tq * 64 + nf * 16 + lr) * CR + kk * 32 + (lg << 3)];
                il_nxt[nf] = ilrow[b * W + tq * 64 + nf * 16 + lr];
            }
            if (it + 1 < NIT) {
                #pragma unroll
                for (int nf = 0; nf < 4; ++nf) {
                    f32x4 s = {};
                    #pragma unroll
                    for (int kk = 0; kk < 2; ++kk)
                        s = mfma16(ak[kk], bq_cur[nf][kk], s);
                    #pragma unroll
                    for (int r = 0; r < 4; ++r)
                        pt[1 - cur][jp + (lg << 2) + r][nf * 16 + lr] =
                            f2bs(__expf(s[r] * SCALE) * il_cur[nf]);
                }
            }
            asm volatile("s_waitcnt lgkmcnt(0)" ::: "memory");
            __builtin_amdgcn_s_barrier();
            asm volatile("" ::: "memory");
            #pragma unroll
            for (int nf = 0; nf < 4; ++nf) {
                #pragma unroll
                for (int kk = 0; kk < 2; ++kk)
                    bq_cur[nf][kk] = bq_nxt[nf][kk];
                il_cur[nf] = il_nxt[nf];
            }
        }
        // producers: no epilogue
    } else {
        // ---------- consumer: 64 c rows, PV from pt[cur] ----------
        const int c0 = (w - 4) * 64;
        bf16x8 av_cur[4][2], av_nxt[4][2];
        #pragma unroll
        for (int mf = 0; mf < 4; ++mf)
            #pragma unroll
            for (int kk = 0; kk < 2; ++kk)
                av_cur[mf][kk] = *(const bf16x8*)&v[(b * C + c0 + mf * 16 + lr) * W + kk * 32 + (lg << 3)];

        asm volatile("s_waitcnt lgkmcnt(0)" ::: "memory");
        __builtin_amdgcn_s_barrier();
        asm volatile("" ::: "memory");

        f32x4 acc[4][4] = {};
        for (int it = 0; it < NIT; ++it) {
            const int cur = it & 1;
            const int tv = (it + 1 < NIT) ? (it + 1) : it;
            #pragma unroll
            for (int mf = 0; mf < 4; ++mf)
                #pragma unroll
                for (int kk = 0; kk < 2; ++kk)
                    av_nxt[mf][kk] = *(const bf16x8*)&v[(b * C + c0 + mf * 16 + lr) * W + tv * 64 + kk * 32 + (lg << 3)];
            __builtin_amdgcn_s_setprio(1);
            #pragma unroll
            for (int kk = 0; kk < 2; ++kk) {
                bf16x8 bp[4];
                #pragma unroll
                for (int nf = 0; nf < 4; ++nf)
                    bp[nf] = *(const bf16x8*)&pt[cur][nf * 16 + lr][kk * 32 + (lg << 3)];
                #pragma unroll
                for (int mf = 0; mf < 4; ++mf)
                    #pragma unroll
                    for (int nf = 0; nf < 4; ++nf)
                        acc[mf][nf] = mfma16(av_cur[mf][kk], bp[nf], acc[mf][nf]);
            }
            __builtin_amdgcn_s_setprio(0);
            asm volatile("s_waitcnt lgkmcnt(0)" ::: "memory");
            __builtin_amdgcn_s_barrier();
            asm volatile("" ::: "memory");
            #pragma unroll
            for (int mf = 0; mf < 4; ++mf)
                #pragma unroll
                for (int kk = 0; kk < 2; ++kk)
                    av_cur[mf][kk] = av_nxt[mf][kk];
        }
        // epilogue: out = acc + x
        #pragma unroll
        for (int mf = 0; mf < 4; ++mf)
            #pragma unroll
            for (int nf = 0; nf < 4; ++nf)
                #pragma unroll
                for (int r = 0; r < 4; ++r) {
                    int c = c0 + mf * 16 + (lg << 2) + r;
                    int j = j0 + nf * 16 + lr;
                    int off = (b * C + c) * W + j;
                    out[off] = acc[mf][nf][r] + x[off];
                }
    }
}

extern "C" void kernel_launch(void* const* d_in, const int* in_sizes, int n_in,
                              void* d_out, int out_size, void* d_ws, size_t ws_size,
                              hipStream_t stream) {
    const float* x  = (const float*)d_in[0];
    const float* wq = (const float*)d_in[1];
    const float* bq = (const float*)d_in[2];
    const float* wk = (const float*)d_in[3];
    const float* bk = (const float*)d_in[4];
    const float* wv = (const float*)d_in[5];
    const float* bv = (const float*)d_in[6];
    float* out = (float*)d_out;

    char* ws = (char*)d_ws;
    ushort* qTw = (ushort*)(ws);                         // 2 MB
    ushort* kTw = (ushort*)(ws + (2u << 20));            // 2 MB
    ushort* vw  = (ushort*)(ws + (4u << 20));            // 16 MB -> ends 20MB

    const size_t NEED = ((size_t)36 << 20) + ((size_t)704 << 10);
    if (ws_size >= NEED) {
        ushort* xbw  = (ushort*)(ws + (20u << 20));
        ushort* wqb  = (ushort*)(ws + (36u << 20));
        ushort* wkb  = (ushort*)(ws + (36u << 20) + (64u << 10));
        ushort* wvb  = (ushort*)(ws + (36u << 20) + (128u << 10));
        float*  ilrw = (float*)(ws + (36u << 20) + (640u << 10));

        cast_w<<<dim3(1024), 256, 0, stream>>>(wq, wk, wv, wqb, wkb, wvb);
        castT_kernel<<<dim3(W / 64, C / 64, B), 256, 0, stream>>>(x, xbw);
        proj_qk2_kernel<<<dim3(W / 64 * B), 128, 0, stream>>>(xbw, wqb, wkb, bq, bk, qTw, kTw);
        proj_v2_kernel<<<dim3(W / 256 * (C / 128) * B), 512, 0, stream>>>(xbw, wvb, bv, vw);
        stats_kernel<<<dim3(W / 64 * B), 512, 0, stream>>>(qTw, kTw, ilrw);
        context_kernel<<<dim3(W / 64 * B), 768, 0, stream>>>(x, qTw, kTw, vw, ilrw, out);
    } else {
        float* ilrw = (float*)(ws + (20u << 20) + (704u << 10));
        proj_qk_kernel<<<dim3(W / 64, B), 256, 0, stream>>>(x, wq, wk, bq, bk, qTw, kTw);
        proj_v_kernel<<<dim3(W / 128, C / 128, B), 256, 0, stream>>>(x, wv, bv, vw);
        stats_kernel<<<dim3(W / 64 * B), 512, 0, stream>>>(qTw, kTw, ilrw);
        context_kernel<<<dim3(W / 64 * B), 768, 0, stream>>>(x, qTw, kTw, vw, ilrw, out);
    }
}